// Round 5
// baseline (10493.751 us; speedup 1.0000x reference)
//
#include <hip/hip_runtime.h>
#include <cstdint>
#include <cstddef>

#define T_SEQ 4096
#define EMB_D 512
#define HDIM 512
#define G4 2048
#define NTAGS 24
#define START_TAG 22
#define STOP_TAG 23
#define NEGV -10000.0f
#define NBLK 32      // persistent blocks per direction
#define HSLICE 16    // hidden units per block
#define SENT 0xFFFFFFFFu   // -NaN bit pattern; |h|<1 can never equal this

// ---------------------------------------------------------------------------
// 1) xg[dir][t][j] = dot(emb[sent[t]], w_ih[j]) + b_ih[j] + b_hh[j]
// ---------------------------------------------------------------------------
__global__ __launch_bounds__(256) void gemm_xg_kernel(
    const int* __restrict__ sent, const float* __restrict__ emb,
    const float* __restrict__ w_ih_f, const float* __restrict__ b_ih_f, const float* __restrict__ b_hh_f,
    const float* __restrict__ w_ih_b, const float* __restrict__ b_ih_b, const float* __restrict__ b_hh_b,
    float* __restrict__ xg)
{
    const int dir = blockIdx.z;
    const float* W  = dir ? w_ih_b : w_ih_f;
    const float* bi = dir ? b_ih_b : b_ih_f;
    const float* bh = dir ? b_hh_b : b_hh_f;
    const int m0 = blockIdx.y * 64;   // t
    const int n0 = blockIdx.x * 64;   // gate row j
    const int tid = threadIdx.x;

    __shared__ __attribute__((aligned(16))) float As[32][64];  // [k][t]
    __shared__ __attribute__((aligned(16))) float Bs[32][64];  // [k][j]

    const int lrow = tid >> 2;          // 0..63
    const int lk   = (tid & 3) * 8;     // 0,8,16,24

    const int srow = sent[m0 + lrow];
    const float* aptr = emb + (size_t)srow * EMB_D + lk;
    const float* bptr = W   + (size_t)(n0 + lrow) * EMB_D + lk;

    const int ty = tid >> 4;   // 0..15 (M)
    const int tx = tid & 15;   // 0..15 (N)

    float acc[4][4];
    #pragma unroll
    for (int i = 0; i < 4; ++i)
        #pragma unroll
        for (int j = 0; j < 4; ++j) acc[i][j] = 0.f;

    for (int kk = 0; kk < EMB_D; kk += 32) {
        float4 a0 = *(const float4*)(aptr + kk);
        float4 a1 = *(const float4*)(aptr + kk + 4);
        float4 b0 = *(const float4*)(bptr + kk);
        float4 b1 = *(const float4*)(bptr + kk + 4);
        __syncthreads();   // previous iteration's compute done before overwrite
        As[lk+0][lrow]=a0.x; As[lk+1][lrow]=a0.y; As[lk+2][lrow]=a0.z; As[lk+3][lrow]=a0.w;
        As[lk+4][lrow]=a1.x; As[lk+5][lrow]=a1.y; As[lk+6][lrow]=a1.z; As[lk+7][lrow]=a1.w;
        Bs[lk+0][lrow]=b0.x; Bs[lk+1][lrow]=b0.y; Bs[lk+2][lrow]=b0.z; Bs[lk+3][lrow]=b0.w;
        Bs[lk+4][lrow]=b1.x; Bs[lk+5][lrow]=b1.y; Bs[lk+6][lrow]=b1.z; Bs[lk+7][lrow]=b1.w;
        __syncthreads();
        #pragma unroll
        for (int k = 0; k < 32; ++k) {
            float4 av = *(const float4*)&As[k][ty*4];
            float4 bv = *(const float4*)&Bs[k][tx*4];
            acc[0][0]+=av.x*bv.x; acc[0][1]+=av.x*bv.y; acc[0][2]+=av.x*bv.z; acc[0][3]+=av.x*bv.w;
            acc[1][0]+=av.y*bv.x; acc[1][1]+=av.y*bv.y; acc[1][2]+=av.y*bv.z; acc[1][3]+=av.y*bv.w;
            acc[2][0]+=av.z*bv.x; acc[2][1]+=av.z*bv.y; acc[2][2]+=av.z*bv.z; acc[2][3]+=av.z*bv.w;
            acc[3][0]+=av.w*bv.x; acc[3][1]+=av.w*bv.y; acc[3][2]+=av.w*bv.z; acc[3][3]+=av.w*bv.w;
        }
    }
    #pragma unroll
    for (int i = 0; i < 4; ++i) {
        const int t = m0 + ty*4 + i;
        float* crow = xg + ((size_t)dir*T_SEQ + t) * G4 + n0 + tx*4;
        #pragma unroll
        for (int j = 0; j < 4; ++j) {
            const int jg = n0 + tx*4 + j;
            crow[j] = acc[i][j] + bi[jg] + bh[jg];
        }
    }
}

// ---------------------------------------------------------------------------
// 2) Bidirectional LSTM, 64 persistent blocks (32/dir), data-is-the-flag sync
//    (R2 structure). R5 change: waves_per_eu(2,2) [VGPR budget 256, from R4]
//    PLUS asm pins on the 64 weight floats [from R3]. R3's pins spilled at a
//    ~60-reg budget; R4's budget alone let the allocator keep remat'ing the
//    weight loads into the step loop (VGPR=88, time unchanged). Theory: the
//    per-step 128 KB/block weight re-stream from L2 (~0.95 us at ~135 GB/s
//    per CU) is the dominant step cost; pinning kills it.
// ---------------------------------------------------------------------------
__global__ __attribute__((amdgpu_waves_per_eu(2, 2))) __launch_bounds__(512)
void bilstm_kernel(
    const float* __restrict__ w_hh_f, const float* __restrict__ w_hh_b,
    const float* __restrict__ h0, const float* __restrict__ c0,
    const float* __restrict__ xg,
    uint32_t* __restrict__ h_hist)   // [2][T][HDIM] float bits, pre-set SENT
{
    const int blk = blockIdx.x;
    const int dir = blk >> 5;
    const int b   = blk & 31;
    const int tid = threadIdx.x;    // 512
    const int q   = tid >> 6;       // 0..7 : 64-wide slice of h
    const int rl  = tid & 63;       // 0..63: local gate row
    const int g2  = rl >> 4;        // 0..3 : i,f,g,o
    const int hu  = rl & 15;
    const int row = g2 * HDIM + b * HSLICE + hu;   // global gate row

    const float* Wrow = (dir ? w_hh_b : w_hh_f) + (size_t)row * HDIM + q * 64;
    float w[64];
    #pragma unroll
    for (int j = 0; j < 16; ++j) {
        float4 v = ((const float4*)Wrow)[j];
        w[4*j+0]=v.x; w[4*j+1]=v.y; w[4*j+2]=v.z; w[4*j+3]=v.w;
    }
    // Pin weights in VGPRs. With waves_per_eu(2,2) the per-wave budget is
    // 256 regs (512-thread block = 8 waves = 2/EU exactly), so 64 pinned +
    // working set fits without the scratch spills R3 hit at a ~60-reg budget.
    #pragma unroll
    for (int i = 0; i < 64; ++i) asm volatile("" : "+v"(w[i]));

    __shared__ __attribute__((aligned(16))) float hbuf[512];
    __shared__ float part[512];

    float c = (tid < HSLICE) ? c0[dir*HDIM + b*HSLICE + tid] : 0.f;

    const float* xgd = xg + (size_t)dir * T_SEQ * G4;
    uint32_t* hh = h_hist + (size_t)dir * T_SEQ * HDIM;

    for (int idx = 0; idx < T_SEQ; ++idx) {
        const int t = dir ? (T_SEQ - 1 - idx) : idx;
        // prefetch xg (independent of h) so it overlaps the poll wait
        float xv = 0.f;
        if (tid < 64) xv = xgd[(size_t)t * G4 + row];

        if (idx == 0) {
            hbuf[tid] = h0[dir*HDIM + tid];
        } else {
            const int tprev = dir ? (t + 1) : (t - 1);
            const uint32_t* wp = hh + (size_t)tprev*HDIM + tid;
            uint32_t u;
            do {
                u = __hip_atomic_load(wp, __ATOMIC_RELAXED, __HIP_MEMORY_SCOPE_AGENT);
            } while (u == SENT);
            union { uint32_t u; float f; } cv; cv.u = u;
            hbuf[tid] = cv.f;
        }
        __syncthreads();                       // B1: hbuf ready

        float s = 0.f;
        const float4* hb4 = (const float4*)&hbuf[q*64];
        #pragma unroll
        for (int j = 0; j < 16; ++j) {
            float4 hv = hb4[j];                // same addr across wave: LDS broadcast
            s += w[4*j+0]*hv.x + w[4*j+1]*hv.y + w[4*j+2]*hv.z + w[4*j+3]*hv.w;
        }
        part[tid] = s;                         // part[q*64+rl] == part[tid]
        __syncthreads();                       // B2: partials ready

        if (tid < 64) {                        // wave 0 only
            float g = xv;
            #pragma unroll
            for (int qq = 0; qq < 8; ++qq) g += part[qq*64 + tid];
            g = (g2 == 2) ? tanhf(g) : 1.f/(1.f + expf(-g));
            // gates for hidden unit hu live at lanes hu, hu+16, hu+32, hu+48
            float iv = __shfl(g, hu);
            float fg = __shfl(g, hu + 16);
            float gv = __shfl(g, hu + 32);
            float ov = __shfl(g, hu + 48);
            if (tid < HSLICE) {
                c = fg*c + iv*gv;
                union { float f; uint32_t u; } hb; hb.f = ov * tanhf(c);
                __hip_atomic_store(hh + (size_t)t*HDIM + b*HSLICE + tid, hb.u,
                                   __ATOMIC_RELAXED, __HIP_MEMORY_SCOPE_AGENT);
            }
        }
        // no trailing barrier: hbuf/part rewrite hazards are covered by B1/B2
        // of the next iteration (writers must pass this iter's barriers first)
    }
}

// ---------------------------------------------------------------------------
// 3) feats[t][tag] = b_tag[tag] + [hf|hb] . w_tag[tag]
// ---------------------------------------------------------------------------
__global__ __launch_bounds__(256) void feats_kernel(
    const float* __restrict__ h_hist, const float* __restrict__ w_tag,
    const float* __restrict__ b_tag, float* __restrict__ feats)
{
    const int t = blockIdx.x;
    const int tid = threadIdx.x;
    __shared__ __attribute__((aligned(16))) float h[1024];
    __shared__ float partl[192];
    for (int i = tid; i < 512; i += 256) {
        h[i]     = h_hist[(size_t)t*HDIM + i];
        h[512+i] = h_hist[(size_t)T_SEQ*HDIM + (size_t)t*HDIM + i];
    }
    __syncthreads();
    if (tid < 192) {
        const int tag = tid >> 3, p = tid & 7;
        const float* wr = w_tag + (size_t)tag*1024 + p*128;
        const float* hp = h + p*128;
        float s = 0.f;
        #pragma unroll 8
        for (int j = 0; j < 128; ++j) s += wr[j]*hp[j];
        partl[tid] = s;
    }
    __syncthreads();
    if (tid < NTAGS) {
        float s = b_tag[tid];
        #pragma unroll
        for (int p = 0; p < 8; ++p) s += partl[tid*8+p];
        feats[(size_t)t*NTAGS + tid] = s;
    }
}

// ---------------------------------------------------------------------------
// 4) Viterbi forward: single wave, barrier-free/LDS-free via shfl broadcast.
//    Strict > keeps FIRST argmax (matches jnp.argmax tie-break).
// ---------------------------------------------------------------------------
__global__ void viterbi_fwd_kernel(
    const float* __restrict__ feats, const float* __restrict__ trans,
    float* __restrict__ d_out, unsigned char* __restrict__ bp,
    int* __restrict__ best_tag)
{
    const int lane = threadIdx.x;       // 64 threads = 1 wave
    const bool act = lane < NTAGS;
    float tr[NTAGS];
    #pragma unroll
    for (int p = 0; p < NTAGS; ++p)
        tr[p] = act ? trans[lane*NTAGS + p] : NEGV;

    float fv = (lane == START_TAG) ? 0.f : NEGV;   // lanes >=24: NEGV, never read

    float ftn = act ? feats[lane] : 0.f;   // prefetch t=0
    for (int t = 0; t < T_SEQ; ++t) {
        float ft = ftn;
        if (act && t + 1 < T_SEQ) ftn = feats[(size_t)(t+1)*NTAGS + lane];
        float bestv = -3.4e38f;
        int argp = 0;
        #pragma unroll
        for (int p = 0; p < NTAGS; ++p) {
            float sc = tr[p] + __shfl(fv, p, 64);
            if (sc > bestv) { bestv = sc; argp = p; }
        }
        fv = bestv + ft;
        if (act) bp[(size_t)t*NTAGS + lane] = (unsigned char)argp;
    }
    if (act) fv += trans[STOP_TAG*NTAGS + lane];
    // lane 0 scans the 24 terminal scores via shuffles
    float bv = __shfl(fv, 0, 64); int bi = 0;
    #pragma unroll
    for (int p = 1; p < NTAGS; ++p) {
        float v = __shfl(fv, p, 64);
        if (v > bv) { bv = v; bi = p; }
    }
    if (lane == 0) {
        d_out[0] = bv;
        *best_tag = bi;
    }
}

// ---------------------------------------------------------------------------
// 5) Hierarchical backtrack
// ---------------------------------------------------------------------------
__global__ void bt_compose_kernel(const unsigned char* __restrict__ bp,
                                  unsigned char* __restrict__ segmap)
{
    const int s = blockIdx.x;
    const int tid = threadIdx.x;   // 64
    __shared__ __attribute__((aligned(16))) unsigned char lbp[64*NTAGS];
    const uint32_t* src = (const uint32_t*)(bp + (size_t)s * 64 * NTAGS);
    uint32_t* dst = (uint32_t*)lbp;
    #pragma unroll
    for (int i = 0; i < 6; ++i) dst[tid + 64*i] = src[tid + 64*i];
    __syncthreads();
    if (tid < NTAGS) {
        int m = tid;
        for (int tt = 63; tt >= 0; --tt) m = lbp[tt*NTAGS + m];
        segmap[s*NTAGS + tid] = (unsigned char)m;
    }
}

__global__ void bt_final_kernel(const unsigned char* __restrict__ segmap,
                                const int* __restrict__ best_tag,
                                int* __restrict__ end_tags)
{
    if (threadIdx.x == 0) {
        int tag = *best_tag;
        end_tags[63] = tag;
        for (int s = 63; s >= 1; --s) {
            tag = segmap[s*NTAGS + tag];
            end_tags[s-1] = tag;
        }
    }
}

__global__ void bt_write_kernel(const unsigned char* __restrict__ bp,
                                const int* __restrict__ end_tags,
                                float* __restrict__ out_path)
{
    const int s = blockIdx.x;
    const int tid = threadIdx.x;   // 64
    __shared__ __attribute__((aligned(16))) unsigned char lbp[64*NTAGS];
    const uint32_t* src = (const uint32_t*)(bp + (size_t)s * 64 * NTAGS);
    uint32_t* dst = (uint32_t*)lbp;
    #pragma unroll
    for (int i = 0; i < 6; ++i) dst[tid + 64*i] = src[tid + 64*i];
    __syncthreads();
    if (tid == 0) {
        int tag = end_tags[s];
        out_path[s*64 + 63] = (float)tag;
        for (int tt = 63; tt >= 1; --tt) {
            tag = lbp[tt*NTAGS + tag];
            out_path[s*64 + tt - 1] = (float)tag;
        }
    }
}

// ---------------------------------------------------------------------------
extern "C" void kernel_launch(void* const* d_in, const int* in_sizes, int n_in,
                              void* d_out, int out_size, void* d_ws, size_t ws_size,
                              hipStream_t stream)
{
    const int*   sent   = (const int*)d_in[0];
    const float* emb    = (const float*)d_in[1];
    const float* w_ih_f = (const float*)d_in[2];
    const float* w_hh_f = (const float*)d_in[3];
    const float* b_ih_f = (const float*)d_in[4];
    const float* b_hh_f = (const float*)d_in[5];
    const float* w_ih_b = (const float*)d_in[6];
    const float* w_hh_b = (const float*)d_in[7];
    const float* b_ih_b = (const float*)d_in[8];
    const float* b_hh_b = (const float*)d_in[9];
    const float* w_tag  = (const float*)d_in[10];
    const float* b_tag  = (const float*)d_in[11];
    const float* trans  = (const float*)d_in[12];
    const float* h0     = (const float*)d_in[13];
    const float* c0     = (const float*)d_in[14];
    float* out = (float*)d_out;

    char* ws = (char*)d_ws;
    size_t off = 0;
    auto alloc = [&](size_t bytes) {
        char* p = ws + off; off += (bytes + 255) & ~(size_t)255; return p;
    };
    float* xg      = (float*)alloc((size_t)2*T_SEQ*G4*sizeof(float));      // 64 MB
    uint32_t* h_hist = (uint32_t*)alloc((size_t)2*T_SEQ*HDIM*sizeof(float)); // 16 MB
    float* feats   = (float*)alloc((size_t)T_SEQ*NTAGS*sizeof(float));
    unsigned char* bp     = (unsigned char*)alloc((size_t)T_SEQ*NTAGS);
    unsigned char* segmap = (unsigned char*)alloc(64*NTAGS);
    int* best_tag = (int*)alloc(sizeof(int));
    int* end_tags = (int*)alloc(64*sizeof(int));

    if (off > ws_size) {   // diagnostic sentinel: workspace too small
        hipMemsetAsync(d_out, 0xFF, 4, stream);
        return;
    }

    // h_hist = 0xFFFFFFFF sentinel (data-is-the-flag; harness poison is 0xAA)
    hipMemsetAsync(h_hist, 0xFF, (size_t)2*T_SEQ*HDIM*sizeof(float), stream);

    dim3 gg(G4/64, T_SEQ/64, 2);
    gemm_xg_kernel<<<gg, 256, 0, stream>>>(sent, emb,
        w_ih_f, b_ih_f, b_hh_f, w_ih_b, b_ih_b, b_hh_b, xg);
    bilstm_kernel<<<64, 512, 0, stream>>>(w_hh_f, w_hh_b, h0, c0, xg, h_hist);
    feats_kernel<<<T_SEQ, 256, 0, stream>>>((const float*)h_hist, w_tag, b_tag, feats);
    viterbi_fwd_kernel<<<1, 64, 0, stream>>>(feats, trans, out, bp, best_tag);
    bt_compose_kernel<<<64, 64, 0, stream>>>(bp, segmap);
    bt_final_kernel<<<1, 64, 0, stream>>>(segmap, best_tag, end_tags);
    bt_write_kernel<<<64, 64, 0, stream>>>(bp, end_tags, out + 1);
}

// Round 6
// 8697.304 us; speedup vs baseline: 1.2066x; 1.2066x over previous
//
#include <hip/hip_runtime.h>
#include <cstdint>
#include <cstddef>

#define T_SEQ 4096
#define EMB_D 512
#define HDIM 512
#define G4 2048
#define NTAGS 24
#define START_TAG 22
#define STOP_TAG 23
#define NEGV -10000.0f
#define NBLK 32      // persistent blocks per direction
#define HSLICE 16    // hidden units per block
#define SENT 0xFFFFFFFFu   // -NaN bit pattern; |h|<1 can never equal this

// ---------------------------------------------------------------------------
// 1) xg[dir][t][j] = dot(emb[sent[t]], w_ih[j]) + b_ih[j] + b_hh[j]
// ---------------------------------------------------------------------------
__global__ __launch_bounds__(256) void gemm_xg_kernel(
    const int* __restrict__ sent, const float* __restrict__ emb,
    const float* __restrict__ w_ih_f, const float* __restrict__ b_ih_f, const float* __restrict__ b_hh_f,
    const float* __restrict__ w_ih_b, const float* __restrict__ b_ih_b, const float* __restrict__ b_hh_b,
    float* __restrict__ xg)
{
    const int dir = blockIdx.z;
    const float* W  = dir ? w_ih_b : w_ih_f;
    const float* bi = dir ? b_ih_b : b_ih_f;
    const float* bh = dir ? b_hh_b : b_hh_f;
    const int m0 = blockIdx.y * 64;   // t
    const int n0 = blockIdx.x * 64;   // gate row j
    const int tid = threadIdx.x;

    __shared__ __attribute__((aligned(16))) float As[32][64];  // [k][t]
    __shared__ __attribute__((aligned(16))) float Bs[32][64];  // [k][j]

    const int lrow = tid >> 2;          // 0..63
    const int lk   = (tid & 3) * 8;     // 0,8,16,24

    const int srow = sent[m0 + lrow];
    const float* aptr = emb + (size_t)srow * EMB_D + lk;
    const float* bptr = W   + (size_t)(n0 + lrow) * EMB_D + lk;

    const int ty = tid >> 4;   // 0..15 (M)
    const int tx = tid & 15;   // 0..15 (N)

    float acc[4][4];
    #pragma unroll
    for (int i = 0; i < 4; ++i)
        #pragma unroll
        for (int j = 0; j < 4; ++j) acc[i][j] = 0.f;

    for (int kk = 0; kk < EMB_D; kk += 32) {
        float4 a0 = *(const float4*)(aptr + kk);
        float4 a1 = *(const float4*)(aptr + kk + 4);
        float4 b0 = *(const float4*)(bptr + kk);
        float4 b1 = *(const float4*)(bptr + kk + 4);
        __syncthreads();   // previous iteration's compute done before overwrite
        As[lk+0][lrow]=a0.x; As[lk+1][lrow]=a0.y; As[lk+2][lrow]=a0.z; As[lk+3][lrow]=a0.w;
        As[lk+4][lrow]=a1.x; As[lk+5][lrow]=a1.y; As[lk+6][lrow]=a1.z; As[lk+7][lrow]=a1.w;
        Bs[lk+0][lrow]=b0.x; Bs[lk+1][lrow]=b0.y; Bs[lk+2][lrow]=b0.z; Bs[lk+3][lrow]=b0.w;
        Bs[lk+4][lrow]=b1.x; Bs[lk+5][lrow]=b1.y; Bs[lk+6][lrow]=b1.z; Bs[lk+7][lrow]=b1.w;
        __syncthreads();
        #pragma unroll
        for (int k = 0; k < 32; ++k) {
            float4 av = *(const float4*)&As[k][ty*4];
            float4 bv = *(const float4*)&Bs[k][tx*4];
            acc[0][0]+=av.x*bv.x; acc[0][1]+=av.x*bv.y; acc[0][2]+=av.x*bv.z; acc[0][3]+=av.x*bv.w;
            acc[1][0]+=av.y*bv.x; acc[1][1]+=av.y*bv.y; acc[1][2]+=av.y*bv.z; acc[1][3]+=av.y*bv.w;
            acc[2][0]+=av.z*bv.x; acc[2][1]+=av.z*bv.y; acc[2][2]+=av.z*bv.z; acc[2][3]+=av.z*bv.w;
            acc[3][0]+=av.w*bv.x; acc[3][1]+=av.w*bv.y; acc[3][2]+=av.w*bv.z; acc[3][3]+=av.w*bv.w;
        }
    }
    #pragma unroll
    for (int i = 0; i < 4; ++i) {
        const int t = m0 + ty*4 + i;
        float* crow = xg + ((size_t)dir*T_SEQ + t) * G4 + n0 + tx*4;
        #pragma unroll
        for (int j = 0; j < 4; ++j) {
            const int jg = n0 + tx*4 + j;
            crow[j] = acc[i][j] + bi[jg] + bh[jg];
        }
    }
}

// ---------------------------------------------------------------------------
// 2) Bidirectional LSTM with XCD co-location. 512 blocks launched; each block
//    reads HW_REG_XCC_ID and claims a rank on its XCD. XCD0 ranks 0..31 run
//    the forward direction, XCD1 ranks 0..31 the backward; all others exit.
//    Producer h-stores and consumer polls then meet in the SAME XCD's L2
//    (agent scope = L2 coherence point), cutting the per-step store->poll
//    visibility latency from cross-XCD (~600-900ns) to intra-XCD (~100-200ns).
//    No deadlock: <=32 participants/XCD at 1 block/CU (waves_per_eu(2,2) =
//    8 waves/CU); queued stragglers run+exit after participants finish.
//    Inner structure = R5 (data-is-the-flag poll, pinned weights, 2 barriers).
// ---------------------------------------------------------------------------
__global__ __attribute__((amdgpu_waves_per_eu(2, 2))) __launch_bounds__(512)
void bilstm_kernel(
    const float* __restrict__ w_hh_f, const float* __restrict__ w_hh_b,
    const float* __restrict__ h0, const float* __restrict__ c0,
    const float* __restrict__ xg,
    uint32_t* __restrict__ h_hist,   // [2][T][HDIM] float bits, pre-set SENT
    int* __restrict__ claim)         // [8] per-XCD rank counters, pre-zeroed
{
    uint32_t xcc;
    asm volatile("s_getreg_b32 %0, hwreg(HW_REG_XCC_ID)" : "=s"(xcc));
    xcc &= 7u;

    __shared__ int rank_s;
    if (threadIdx.x == 0)
        rank_s = __hip_atomic_fetch_add(&claim[xcc], 1, __ATOMIC_RELAXED,
                                        __HIP_MEMORY_SCOPE_AGENT);
    __syncthreads();
    const int rank = rank_s;

    int dir;
    if (xcc == 0) dir = 0;
    else if (xcc == 1) dir = 1;
    else return;
    if (rank >= NBLK) return;
    const int b = rank;

    const int tid = threadIdx.x;    // 512
    const int q   = tid >> 6;       // 0..7 : 64-wide slice of h
    const int rl  = tid & 63;       // 0..63: local gate row
    const int g2  = rl >> 4;        // 0..3 : i,f,g,o
    const int hu  = rl & 15;
    const int row = g2 * HDIM + b * HSLICE + hu;   // global gate row

    const float* Wrow = (dir ? w_hh_b : w_hh_f) + (size_t)row * HDIM + q * 64;
    float w[64];
    #pragma unroll
    for (int j = 0; j < 16; ++j) {
        float4 v = ((const float4*)Wrow)[j];
        w[4*j+0]=v.x; w[4*j+1]=v.y; w[4*j+2]=v.z; w[4*j+3]=v.w;
    }
    // Pin weights in VGPRs (R5: 7.17->6.63ms; budget 256 via waves_per_eu(2,2))
    #pragma unroll
    for (int i = 0; i < 64; ++i) asm volatile("" : "+v"(w[i]));

    __shared__ __attribute__((aligned(16))) float hbuf[512];
    __shared__ float part[512];

    float c = (tid < HSLICE) ? c0[dir*HDIM + b*HSLICE + tid] : 0.f;

    const float* xgd = xg + (size_t)dir * T_SEQ * G4;
    uint32_t* hh = h_hist + (size_t)dir * T_SEQ * HDIM;

    for (int idx = 0; idx < T_SEQ; ++idx) {
        const int t = dir ? (T_SEQ - 1 - idx) : idx;
        // prefetch xg (independent of h) so it overlaps the poll wait
        float xv = 0.f;
        if (tid < 64) xv = xgd[(size_t)t * G4 + row];

        if (idx == 0) {
            hbuf[tid] = h0[dir*HDIM + tid];
        } else {
            const int tprev = dir ? (t + 1) : (t - 1);
            const uint32_t* wp = hh + (size_t)tprev*HDIM + tid;
            uint32_t u;
            do {
                u = __hip_atomic_load(wp, __ATOMIC_RELAXED, __HIP_MEMORY_SCOPE_AGENT);
            } while (u == SENT);
            union { uint32_t u; float f; } cv; cv.u = u;
            hbuf[tid] = cv.f;
        }
        __syncthreads();                       // B1: hbuf ready

        float s = 0.f;
        const float4* hb4 = (const float4*)&hbuf[q*64];
        #pragma unroll
        for (int j = 0; j < 16; ++j) {
            float4 hv = hb4[j];                // same addr across wave: LDS broadcast
            s += w[4*j+0]*hv.x + w[4*j+1]*hv.y + w[4*j+2]*hv.z + w[4*j+3]*hv.w;
        }
        part[tid] = s;                         // part[q*64+rl] == part[tid]
        __syncthreads();                       // B2: partials ready

        if (tid < 64) {                        // wave 0 only
            float g = xv;
            #pragma unroll
            for (int qq = 0; qq < 8; ++qq) g += part[qq*64 + tid];
            g = (g2 == 2) ? tanhf(g) : 1.f/(1.f + expf(-g));
            // gates for hidden unit hu live at lanes hu, hu+16, hu+32, hu+48
            float iv = __shfl(g, hu);
            float fg = __shfl(g, hu + 16);
            float gv = __shfl(g, hu + 32);
            float ov = __shfl(g, hu + 48);
            if (tid < HSLICE) {
                c = fg*c + iv*gv;
                union { float f; uint32_t u; } hb; hb.f = ov * tanhf(c);
                __hip_atomic_store(hh + (size_t)t*HDIM + b*HSLICE + tid, hb.u,
                                   __ATOMIC_RELAXED, __HIP_MEMORY_SCOPE_AGENT);
            }
        }
        // no trailing barrier: hbuf/part rewrite hazards are covered by B1/B2
        // of the next iteration (writers must pass this iter's barriers first)
    }
}

// ---------------------------------------------------------------------------
// 3) feats[t][tag] = b_tag[tag] + [hf|hb] . w_tag[tag]
// ---------------------------------------------------------------------------
__global__ __launch_bounds__(256) void feats_kernel(
    const float* __restrict__ h_hist, const float* __restrict__ w_tag,
    const float* __restrict__ b_tag, float* __restrict__ feats)
{
    const int t = blockIdx.x;
    const int tid = threadIdx.x;
    __shared__ __attribute__((aligned(16))) float h[1024];
    __shared__ float partl[192];
    for (int i = tid; i < 512; i += 256) {
        h[i]     = h_hist[(size_t)t*HDIM + i];
        h[512+i] = h_hist[(size_t)T_SEQ*HDIM + (size_t)t*HDIM + i];
    }
    __syncthreads();
    if (tid < 192) {
        const int tag = tid >> 3, p = tid & 7;
        const float* wr = w_tag + (size_t)tag*1024 + p*128;
        const float* hp = h + p*128;
        float s = 0.f;
        #pragma unroll 8
        for (int j = 0; j < 128; ++j) s += wr[j]*hp[j];
        partl[tid] = s;
    }
    __syncthreads();
    if (tid < NTAGS) {
        float s = b_tag[tid];
        #pragma unroll
        for (int p = 0; p < 8; ++p) s += partl[tid*8+p];
        feats[(size_t)t*NTAGS + tid] = s;
    }
}

// ---------------------------------------------------------------------------
// 4) Viterbi forward: single wave, LDS broadcast (R2 version — the R5 shfl
//    rewrite regressed 1.6ms; reverted). Strict > keeps FIRST argmax.
// ---------------------------------------------------------------------------
__global__ void viterbi_fwd_kernel(
    const float* __restrict__ feats, const float* __restrict__ trans,
    float* __restrict__ d_out, unsigned char* __restrict__ bp,
    int* __restrict__ best_tag)
{
    const int lane = threadIdx.x;       // 64 threads = 1 wave
    const bool act = lane < NTAGS;
    float tr[NTAGS];
    #pragma unroll
    for (int p = 0; p < NTAGS; ++p)
        tr[p] = act ? trans[lane*NTAGS + p] : NEGV;

    float fv = (lane == START_TAG) ? 0.f : NEGV;
    __shared__ float fvs[NTAGS];
    __shared__ float term[NTAGS];

    float ftn = act ? feats[lane] : 0.f;   // prefetch t=0
    for (int t = 0; t < T_SEQ; ++t) {
        if (act) fvs[lane] = fv;
        __syncthreads();
        float ft = ftn;
        if (act && t + 1 < T_SEQ) ftn = feats[(size_t)(t+1)*NTAGS + lane];
        float bestv = -3.4e38f;
        int argp = 0;
        #pragma unroll
        for (int p = 0; p < NTAGS; ++p) {
            float sc = tr[p] + fvs[p];
            if (sc > bestv) { bestv = sc; argp = p; }
        }
        __syncthreads();   // reads done before next iteration's write
        fv = bestv + ft;
        if (act) bp[(size_t)t*NTAGS + lane] = (unsigned char)argp;
    }
    if (act) { fv += trans[STOP_TAG*NTAGS + lane]; term[lane] = fv; }
    __syncthreads();
    if (lane == 0) {
        float bv = term[0]; int bi = 0;
        #pragma unroll
        for (int p = 1; p < NTAGS; ++p) if (term[p] > bv) { bv = term[p]; bi = p; }
        d_out[0] = bv;
        *best_tag = bi;
    }
}

// ---------------------------------------------------------------------------
// 5) Hierarchical backtrack
// ---------------------------------------------------------------------------
__global__ void bt_compose_kernel(const unsigned char* __restrict__ bp,
                                  unsigned char* __restrict__ segmap)
{
    const int s = blockIdx.x;
    const int tid = threadIdx.x;   // 64
    __shared__ __attribute__((aligned(16))) unsigned char lbp[64*NTAGS];
    const uint32_t* src = (const uint32_t*)(bp + (size_t)s * 64 * NTAGS);
    uint32_t* dst = (uint32_t*)lbp;
    #pragma unroll
    for (int i = 0; i < 6; ++i) dst[tid + 64*i] = src[tid + 64*i];
    __syncthreads();
    if (tid < NTAGS) {
        int m = tid;
        for (int tt = 63; tt >= 0; --tt) m = lbp[tt*NTAGS + m];
        segmap[s*NTAGS + tid] = (unsigned char)m;
    }
}

__global__ void bt_final_kernel(const unsigned char* __restrict__ segmap,
                                const int* __restrict__ best_tag,
                                int* __restrict__ end_tags)
{
    if (threadIdx.x == 0) {
        int tag = *best_tag;
        end_tags[63] = tag;
        for (int s = 63; s >= 1; --s) {
            tag = segmap[s*NTAGS + tag];
            end_tags[s-1] = tag;
        }
    }
}

__global__ void bt_write_kernel(const unsigned char* __restrict__ bp,
                                const int* __restrict__ end_tags,
                                float* __restrict__ out_path)
{
    const int s = blockIdx.x;
    const int tid = threadIdx.x;   // 64
    __shared__ __attribute__((aligned(16))) unsigned char lbp[64*NTAGS];
    const uint32_t* src = (const uint32_t*)(bp + (size_t)s * 64 * NTAGS);
    uint32_t* dst = (uint32_t*)lbp;
    #pragma unroll
    for (int i = 0; i < 6; ++i) dst[tid + 64*i] = src[tid + 64*i];
    __syncthreads();
    if (tid == 0) {
        int tag = end_tags[s];
        out_path[s*64 + 63] = (float)tag;
        for (int tt = 63; tt >= 1; --tt) {
            tag = lbp[tt*NTAGS + tag];
            out_path[s*64 + tt - 1] = (float)tag;
        }
    }
}

// ---------------------------------------------------------------------------
extern "C" void kernel_launch(void* const* d_in, const int* in_sizes, int n_in,
                              void* d_out, int out_size, void* d_ws, size_t ws_size,
                              hipStream_t stream)
{
    const int*   sent   = (const int*)d_in[0];
    const float* emb    = (const float*)d_in[1];
    const float* w_ih_f = (const float*)d_in[2];
    const float* w_hh_f = (const float*)d_in[3];
    const float* b_ih_f = (const float*)d_in[4];
    const float* b_hh_f = (const float*)d_in[5];
    const float* w_ih_b = (const float*)d_in[6];
    const float* w_hh_b = (const float*)d_in[7];
    const float* b_ih_b = (const float*)d_in[8];
    const float* b_hh_b = (const float*)d_in[9];
    const float* w_tag  = (const float*)d_in[10];
    const float* b_tag  = (const float*)d_in[11];
    const float* trans  = (const float*)d_in[12];
    const float* h0     = (const float*)d_in[13];
    const float* c0     = (const float*)d_in[14];
    float* out = (float*)d_out;

    char* ws = (char*)d_ws;
    size_t off = 0;
    auto alloc = [&](size_t bytes) {
        char* p = ws + off; off += (bytes + 255) & ~(size_t)255; return p;
    };
    float* xg      = (float*)alloc((size_t)2*T_SEQ*G4*sizeof(float));      // 64 MB
    uint32_t* h_hist = (uint32_t*)alloc((size_t)2*T_SEQ*HDIM*sizeof(float)); // 16 MB
    float* feats   = (float*)alloc((size_t)T_SEQ*NTAGS*sizeof(float));
    unsigned char* bp     = (unsigned char*)alloc((size_t)T_SEQ*NTAGS);
    unsigned char* segmap = (unsigned char*)alloc(64*NTAGS);
    int* best_tag = (int*)alloc(sizeof(int));
    int* end_tags = (int*)alloc(64*sizeof(int));
    int* claim    = (int*)alloc(8*sizeof(int));

    if (off > ws_size) {   // diagnostic sentinel: workspace too small
        hipMemsetAsync(d_out, 0xFF, 4, stream);
        return;
    }

    // h_hist = 0xFFFFFFFF sentinel (data-is-the-flag; harness poison is 0xAA)
    hipMemsetAsync(h_hist, 0xFF, (size_t)2*T_SEQ*HDIM*sizeof(float), stream);
    hipMemsetAsync(claim, 0, 8*sizeof(int), stream);

    dim3 gg(G4/64, T_SEQ/64, 2);
    gemm_xg_kernel<<<gg, 256, 0, stream>>>(sent, emb,
        w_ih_f, b_ih_f, b_hh_f, w_ih_b, b_ih_b, b_hh_b, xg);
    bilstm_kernel<<<512, 512, 0, stream>>>(w_hh_f, w_hh_b, h0, c0, xg, h_hist, claim);
    feats_kernel<<<T_SEQ, 256, 0, stream>>>((const float*)h_hist, w_tag, b_tag, feats);
    viterbi_fwd_kernel<<<1, 64, 0, stream>>>(feats, trans, out, bp, best_tag);
    bt_compose_kernel<<<64, 64, 0, stream>>>(bp, segmap);
    bt_final_kernel<<<1, 64, 0, stream>>>(segmap, best_tag, end_tags);
    bt_write_kernel<<<64, 64, 0, stream>>>(bp, end_tags, out + 1);
}